// Round 2
// 318.848 us; speedup vs baseline: 1.1099x; 1.1099x over previous
//
#include <hip/hip_runtime.h>
#include <climits>

#define IN_F 4096
#define OUT_F 4096
#define BATCH 4096
#define NPART 1024   // partial-reduction slots for weight min/max

typedef __bf16 bf16x8 __attribute__((ext_vector_type(8)));
typedef float f32x4 __attribute__((ext_vector_type(4)));

__device__ __forceinline__ unsigned short f2bf_rne(float f) {
  unsigned int u = __float_as_uint(f);
  u += 0x7fffu + ((u >> 16) & 1u);
  return (unsigned short)(u >> 16);
}

// ---------------- fused conversion kernel ----------------
// blocks [0, NPART):        weights int32 -> bf16 (exact), per-block partial min/max
// blocks [NPART, 2*NPART):  x fp32 -> bf16 + per-row sums (1 wave per row, 4 rows/block)
__global__ __launch_bounds__(256) void k_conv(const float* __restrict__ x,
                                              const int* __restrict__ q,
                                              unsigned short* __restrict__ xb,
                                              unsigned short* __restrict__ qb,
                                              float* __restrict__ rowsum,
                                              int* __restrict__ pmin,
                                              int* __restrict__ pmax) {
  if (blockIdx.x < NPART) {
    // ---- weight conversion + min/max partials (no global atomics: R1 showed
    // 16K same-address atomicMin/Max serialize at ~28 cyc each = 383 us) ----
    const int n4 = (OUT_F * IN_F) / 4;
    const int stride = NPART * 256;
    int vmin = INT_MAX, vmax = INT_MIN;
    const int4* q4 = (const int4*)q;
    ushort4* qb4 = (ushort4*)qb;
    for (int i = blockIdx.x * 256 + threadIdx.x; i < n4; i += stride) {
      int4 v = q4[i];
      vmin = min(vmin, min(min(v.x, v.y), min(v.z, v.w)));
      vmax = max(vmax, max(max(v.x, v.y), max(v.z, v.w)));
      ushort4 h;
      h.x = f2bf_rne((float)v.x);  // |q| <= 255 -> exact in bf16
      h.y = f2bf_rne((float)v.y);
      h.z = f2bf_rne((float)v.z);
      h.w = f2bf_rne((float)v.w);
      qb4[i] = h;
    }
    for (int off = 32; off > 0; off >>= 1) {
      vmin = min(vmin, __shfl_down(vmin, off));
      vmax = max(vmax, __shfl_down(vmax, off));
    }
    __shared__ int rmin[4], rmax[4];
    const int wave = threadIdx.x >> 6;
    if ((threadIdx.x & 63) == 0) { rmin[wave] = vmin; rmax[wave] = vmax; }
    __syncthreads();
    if (threadIdx.x == 0) {
      pmin[blockIdx.x] = min(min(rmin[0], rmin[1]), min(rmin[2], rmin[3]));
      pmax[blockIdx.x] = max(max(rmax[0], rmax[1]), max(rmax[2], rmax[3]));
    }
  } else {
    // ---- x conversion + rowsum: wave w handles row 4*b + w ----
    const int wave = threadIdx.x >> 6;
    const int lane = threadIdx.x & 63;
    const int row = (blockIdx.x - NPART) * 4 + wave;
    const float4* xr = (const float4*)(x + (size_t)row * IN_F);
    ushort4* xbr = (ushort4*)(xb + (size_t)row * IN_F);
    float s = 0.f;
#pragma unroll
    for (int it = 0; it < IN_F / 4 / 64; ++it) {
      const int i = it * 64 + lane;
      float4 v = xr[i];
      s += (v.x + v.y) + (v.z + v.w);
      ushort4 h;
      h.x = f2bf_rne(v.x); h.y = f2bf_rne(v.y);
      h.z = f2bf_rne(v.z); h.w = f2bf_rne(v.w);
      xbr[i] = h;
    }
    for (int off = 32; off > 0; off >>= 1) s += __shfl_down(s, off);
    if (lane == 0) rowsum[row] = s;
  }
}

// ---------------- weight min/max only (fallback path, partials) ----------------
__global__ __launch_bounds__(256) void k_wmm(const int* __restrict__ q,
                                             int* __restrict__ pmin,
                                             int* __restrict__ pmax) {
  const int n4 = (OUT_F * IN_F) / 4;
  const int stride = gridDim.x * blockDim.x;
  int vmin = INT_MAX, vmax = INT_MIN;
  const int4* q4 = (const int4*)q;
  for (int i = blockIdx.x * blockDim.x + threadIdx.x; i < n4; i += stride) {
    int4 v = q4[i];
    vmin = min(vmin, min(min(v.x, v.y), min(v.z, v.w)));
    vmax = max(vmax, max(max(v.x, v.y), max(v.z, v.w)));
  }
  for (int off = 32; off > 0; off >>= 1) {
    vmin = min(vmin, __shfl_down(vmin, off));
    vmax = max(vmax, __shfl_down(vmax, off));
  }
  __shared__ int rmin[4], rmax[4];
  const int wave = threadIdx.x >> 6;
  if ((threadIdx.x & 63) == 0) { rmin[wave] = vmin; rmax[wave] = vmax; }
  __syncthreads();
  if (threadIdx.x == 0) {
    pmin[blockIdx.x] = min(min(rmin[0], rmin[1]), min(rmin[2], rmin[3]));
    pmax[blockIdx.x] = max(max(rmax[0], rmax[1]), max(rmax[2], rmax[3]));
  }
}

// ---------------- reduce partials + bias min/max, compute affine scalars ----------------
__global__ __launch_bounds__(256) void k_scal(const int* __restrict__ pmin,
                                              const int* __restrict__ pmax, int npart,
                                              const int* __restrict__ bq,
                                              const float* __restrict__ wmn,
                                              const float* __restrict__ wmx,
                                              const float* __restrict__ bmn,
                                              const float* __restrict__ bmx,
                                              float* __restrict__ scal) {
  int vmin = INT_MAX, vmax = INT_MIN;
  for (int i = threadIdx.x; i < npart; i += 256) {
    vmin = min(vmin, pmin[i]);
    vmax = max(vmax, pmax[i]);
  }
  int bmin = INT_MAX, bmaxv = INT_MIN;
  for (int i = threadIdx.x; i < OUT_F; i += 256) {
    int v = bq[i];
    bmin = min(bmin, v);
    bmaxv = max(bmaxv, v);
  }
  for (int off = 32; off > 0; off >>= 1) {
    vmin = min(vmin, __shfl_down(vmin, off));
    vmax = max(vmax, __shfl_down(vmax, off));
    bmin = min(bmin, __shfl_down(bmin, off));
    bmaxv = max(bmaxv, __shfl_down(bmaxv, off));
  }
  __shared__ int r[4][4];
  const int wave = threadIdx.x >> 6;
  if ((threadIdx.x & 63) == 0) {
    r[wave][0] = vmin; r[wave][1] = vmax; r[wave][2] = bmin; r[wave][3] = bmaxv;
  }
  __syncthreads();
  if (threadIdx.x == 0) {
    int qmin = min(min(r[0][0], r[1][0]), min(r[2][0], r[3][0]));
    int qmax = max(max(r[0][1], r[1][1]), max(r[2][1], r[3][1]));
    int qbmin = min(min(r[0][2], r[1][2]), min(r[2][2], r[3][2]));
    int qbmax = max(max(r[0][3], r[1][3]), max(r[2][3], r[3][3]));
    float ws = (*wmx - *wmn) / (float)(qmax - qmin);
    scal[0] = ws;
    scal[1] = *wmn - ws * (float)qmin;
    float bs = (*bmx - *bmn) / (float)(qbmax - qbmin);
    scal[2] = bs;
    scal[3] = *bmn - bs * (float)qbmin;
  }
}

// ---------------- async global->LDS, 16B per lane, wave-uniform LDS base ----------------
__device__ __forceinline__ void load_lds16(const unsigned short* g, unsigned short* l) {
  __builtin_amdgcn_global_load_lds(
      (const __attribute__((address_space(1))) unsigned int*)g,
      (__attribute__((address_space(3))) unsigned int*)l, 16, 0, 0);
}

// ---------------- 256x256-tile deep-pipelined bf16 MFMA GEMM: C = A @ B^T ----------------
// R4/R5: 8-phase/counted-vmcnt structure (T3+T4+T5). 512 thr / 8 waves (2M x 4N),
// per-wave 128x64 output, BK=32, 4-slot LDS ring (A+B = 32 KB/slot, 128 KB total, 1 blk/CU).
// R5 is an unchanged resubmit: R4's failure was container-level (no pytest/correctness
// output); kernel audit found no hang path (all barriers uniform; vmcnt tail drain
// cannot block) and no OOB.
//
// Schedule invariants (race-freedom proof sketch — do not edit without re-deriving):
//  * group t reads slot t&3; stage-issues for tile t+3 go to slot (t+3)&3 = (t-1)&3,
//    whose last reader was group t-1, separated from the issue by >=1 s_barrier.
//  * end-of-group checkpoint: s_waitcnt vmcnt(8) leaves tiles t+2,t+3 (2x4 loads) in
//    flight and guarantees tile t+1 fully retired; barrier makes it visible. Tail
//    drains 8 -> 4 -> 0 over the last three groups. vmcnt never 0 in steady state.
//  * only VMEM ops inside the loop are the 4 global_load_lds per group (spill-free
//    regalloc required; epilogue loads/stores come after the loop).
// LDS swizzle (both-sides involution, rule 21): physical 16B chunk p of row r holds
// global k-chunk p ^ ((r>>1)&3); ds_read applies the same XOR -> 2 lanes/bank (free).
__global__ __launch_bounds__(512, 2) void k_gemm(
    const unsigned short* __restrict__ A,   // x   bf16 [BATCH][IN_F]
    const unsigned short* __restrict__ B,   // Q   bf16 [OUT_F][IN_F]
    const int* __restrict__ bq,
    const float* __restrict__ rowsum,
    const float* __restrict__ scal,
    float* __restrict__ C) {
  __shared__ __align__(16) unsigned short As[4][8192];   // 4 slots x 256 rows x 32 cols
  __shared__ __align__(16) unsigned short Bs[4][8192];

  const int tid = threadIdx.x;
  const int w = tid >> 6;
  const int lane = tid & 63;
  const int bm = blockIdx.x * 256;
  const int bn = blockIdx.y * 256;

  const int wm = (w & 1) * 128;    // wave's 128x64 output subtile
  const int wn = (w >> 1) * 64;
  const int r16 = lane & 15;
  const int q = lane >> 4;
  // fragment-read swizzled chunk (element offset): chunk q XOR row-bits
  const int pc = (q ^ ((r16 >> 1) & 3)) * 8;

  // staging assignment: wave w covers chunks [w*128, w*128+128) of each 1024-chunk slot
  const int cA0 = w * 128 + lane;
  const int rowS0 = cA0 >> 2;
  const int colS0 = ((cA0 & 3) ^ ((rowS0 >> 1) & 3)) * 8;   // pre-swizzled global source
  const int cA1 = cA0 + 64;
  const int rowS1 = cA1 >> 2;
  const int colS1 = ((cA1 & 3) ^ ((rowS1 >> 1) & 3)) * 8;
  const unsigned short* srcA0 = A + (size_t)(bm + rowS0) * IN_F + colS0;
  const unsigned short* srcA1 = A + (size_t)(bm + rowS1) * IN_F + colS1;
  const unsigned short* srcB0 = B + (size_t)(bn + rowS0) * IN_F + colS0;
  const unsigned short* srcB1 = B + (size_t)(bn + rowS1) * IN_F + colS1;
  const int dst0 = w * 1024;        // ushort offset of wave's chunk block, load 0
  const int dst1 = w * 1024 + 512;  // load 1

  f32x4 acc[8][4] = {};

  const int NT = IN_F / 32;   // 128 K-subtiles

  // prologue: stage tiles 0,1,2 into slots 0,1,2 (12 loads/thread)
#pragma unroll
  for (int t = 0; t < 3; ++t) {
    load_lds16(srcA0 + t * 32, &As[t][dst0]);
    load_lds16(srcA1 + t * 32, &As[t][dst1]);
    load_lds16(srcB0 + t * 32, &Bs[t][dst0]);
    load_lds16(srcB1 + t * 32, &Bs[t][dst1]);
  }
  asm volatile("s_waitcnt vmcnt(8)" ::: "memory");   // tile 0 resident
  __builtin_amdgcn_s_barrier();

  for (int t = 0; t < NT; ++t) {
    const int s = t & 3;
    const unsigned short* Asl = As[s];
    const unsigned short* Bsl = Bs[s];
    const int s3 = (t + 3) & 3;
    const int koff = (t + 3) * 32;
    const bool pf = (t + 3 < NT);

    // ---- phase 0: frags for mi 0-3 + all B frags; stage A-halves of tile t+3 ----
    bf16x8 afr[4], bfr[4];
#pragma unroll
    for (int i = 0; i < 4; ++i)
      afr[i] = *(const bf16x8*)&Asl[(wm + i * 16 + r16) * 32 + pc];
#pragma unroll
    for (int i = 0; i < 4; ++i)
      bfr[i] = *(const bf16x8*)&Bsl[(wn + i * 16 + r16) * 32 + pc];
    if (pf) {
      load_lds16(srcA0 + koff, &As[s3][dst0]);
      load_lds16(srcA1 + koff, &As[s3][dst1]);
    }
    __builtin_amdgcn_s_barrier();
    __builtin_amdgcn_s_setprio(1);
#pragma unroll
    for (int mi = 0; mi < 4; ++mi)
#pragma unroll
      for (int ni = 0; ni < 4; ++ni)
        acc[mi][ni] = __builtin_amdgcn_mfma_f32_16x16x32_bf16(afr[mi], bfr[ni], acc[mi][ni], 0, 0, 0);
    __builtin_amdgcn_s_setprio(0);
    __builtin_amdgcn_s_barrier();

    // ---- phase 1: frags for mi 4-7 (B reused); stage B-halves of tile t+3 ----
    bf16x8 af2[4];
#pragma unroll
    for (int i = 0; i < 4; ++i)
      af2[i] = *(const bf16x8*)&Asl[(wm + 64 + i * 16 + r16) * 32 + pc];
    if (pf) {
      load_lds16(srcB0 + koff, &Bs[s3][dst0]);
      load_lds16(srcB1 + koff, &Bs[s3][dst1]);
    }
    __builtin_amdgcn_s_barrier();
    __builtin_amdgcn_s_setprio(1);
#pragma unroll
    for (int mi = 0; mi < 4; ++mi)
#pragma unroll
      for (int ni = 0; ni < 4; ++ni)
        acc[4 + mi][ni] = __builtin_amdgcn_mfma_f32_16x16x32_bf16(af2[mi], bfr[ni], acc[4 + mi][ni], 0, 0, 0);
    __builtin_amdgcn_s_setprio(0);

    // ---- counted-vmcnt checkpoint: tile t+1 retired, t+2/t+3 stay in flight ----
    if (t < NT - 3)       asm volatile("s_waitcnt vmcnt(8)" ::: "memory");
    else if (t == NT - 3) asm volatile("s_waitcnt vmcnt(4)" ::: "memory");
    else if (t == NT - 2) asm volatile("s_waitcnt vmcnt(0)" ::: "memory");
    __builtin_amdgcn_s_barrier();
  }

  const float wsc = scal[0], wbe = scal[1], bsc = scal[2], bbe = scal[3];
#pragma unroll
  for (int ni = 0; ni < 4; ++ni) {
    const int gn = bn + wn + ni * 16 + r16;            // C/D: col = lane&15
    const float bdq = bsc * (float)bq[gn] + bbe;
#pragma unroll
    for (int mi = 0; mi < 8; ++mi) {
      const int gm0 = bm + wm + mi * 16 + q * 4;       // C/D: row = quad*4 + reg
#pragma unroll
      for (int r = 0; r < 4; ++r) {
        const int gm = gm0 + r;
        C[(size_t)gm * OUT_F + gn] = wsc * acc[mi][ni][r] + wbe * rowsum[gm] + bdq;
      }
    }
  }
}

// ---------------- fallback (workspace too small): dequant-on-the-fly naive GEMM ----------------
__global__ void k_naive(const float* __restrict__ x, const int* __restrict__ wq,
                        const int* __restrict__ bq, const float* __restrict__ scal,
                        float* __restrict__ out) {
  const int o = blockIdx.x * blockDim.x + threadIdx.x;
  const int b = blockIdx.y;
  const float* xr = x + (size_t)b * IN_F;
  const int* wr = wq + (size_t)o * IN_F;
  float s = 0.f, sx = 0.f;
  for (int k = 0; k < IN_F; ++k) {
    float xv = xr[k];
    s += xv * (float)wr[k];
    sx += xv;
  }
  out[(size_t)b * OUT_F + o] =
      scal[0] * s + scal[1] * sx + scal[2] * (float)bq[o] + scal[3];
}

extern "C" void kernel_launch(void* const* d_in, const int* in_sizes, int n_in,
                              void* d_out, int out_size, void* d_ws, size_t ws_size,
                              hipStream_t stream) {
  const float* x = (const float*)d_in[0];
  const int* wq = (const int*)d_in[1];
  const int* bq = (const int*)d_in[2];
  const float* wmn = (const float*)d_in[3];
  const float* wmx = (const float*)d_in[4];
  const float* bmn = (const float*)d_in[5];
  const float* bmx = (const float*)d_in[6];
  float* out = (float*)d_out;

  char* ws = (char*)d_ws;
  float* scal = (float*)ws;                                  // 16 B
  int* pmin = (int*)(ws + 64);                               // 4 KB
  int* pmax = (int*)(ws + 64 + NPART * 4);                   // 4 KB
  float* rowsum = (float*)(ws + 64 + 2 * NPART * 4);         // 16 KB
  unsigned short* xb = (unsigned short*)(ws + 32768);
  unsigned short* qb = xb + (size_t)BATCH * IN_F;
  const size_t needed = 32768 + (size_t)BATCH * IN_F * 2 + (size_t)OUT_F * IN_F * 2;

  if (ws_size >= needed) {
    k_conv<<<2 * NPART, 256, 0, stream>>>(x, wq, xb, qb, rowsum, pmin, pmax);
    k_scal<<<1, 256, 0, stream>>>(pmin, pmax, NPART, bq, wmn, wmx, bmn, bmx, scal);
    dim3 grid(BATCH / 256, OUT_F / 256);
    k_gemm<<<grid, 512, 0, stream>>>(xb, qb, bq, rowsum, scal, out);
  } else {
    k_wmm<<<NPART, 256, 0, stream>>>(wq, pmin, pmax);
    k_scal<<<1, 256, 0, stream>>>(pmin, pmax, NPART, bq, wmn, wmx, bmn, bmx, scal);
    k_naive<<<dim3(OUT_F / 256, BATCH), 256, 0, stream>>>(x, wq, bq, scal, out);
  }
}

// Round 3
// 314.425 us; speedup vs baseline: 1.1255x; 1.0141x over previous
//
#include <hip/hip_runtime.h>
#include <climits>

#define IN_F 4096
#define OUT_F 4096
#define BATCH 4096
#define NPART 1024   // partial-reduction slots for weight min/max

typedef __bf16 bf16x8 __attribute__((ext_vector_type(8)));
typedef float f32x4 __attribute__((ext_vector_type(4)));

__device__ __forceinline__ unsigned short f2bf_rne(float f) {
  unsigned int u = __float_as_uint(f);
  u += 0x7fffu + ((u >> 16) & 1u);
  return (unsigned short)(u >> 16);
}

// ---------------- fused conversion kernel ----------------
// blocks [0, NPART):        weights int32 -> bf16 (exact), per-block partial min/max
// blocks [NPART, 2*NPART):  x fp32 -> bf16 + per-row sums (1 wave per row, 4 rows/block)
__global__ __launch_bounds__(256) void k_conv(const float* __restrict__ x,
                                              const int* __restrict__ q,
                                              unsigned short* __restrict__ xb,
                                              unsigned short* __restrict__ qb,
                                              float* __restrict__ rowsum,
                                              int* __restrict__ pmin,
                                              int* __restrict__ pmax) {
  if (blockIdx.x < NPART) {
    const int n4 = (OUT_F * IN_F) / 4;
    const int stride = NPART * 256;
    int vmin = INT_MAX, vmax = INT_MIN;
    const int4* q4 = (const int4*)q;
    ushort4* qb4 = (ushort4*)qb;
    for (int i = blockIdx.x * 256 + threadIdx.x; i < n4; i += stride) {
      int4 v = q4[i];
      vmin = min(vmin, min(min(v.x, v.y), min(v.z, v.w)));
      vmax = max(vmax, max(max(v.x, v.y), max(v.z, v.w)));
      ushort4 h;
      h.x = f2bf_rne((float)v.x);  // |q| <= 255 -> exact in bf16
      h.y = f2bf_rne((float)v.y);
      h.z = f2bf_rne((float)v.z);
      h.w = f2bf_rne((float)v.w);
      qb4[i] = h;
    }
    for (int off = 32; off > 0; off >>= 1) {
      vmin = min(vmin, __shfl_down(vmin, off));
      vmax = max(vmax, __shfl_down(vmax, off));
    }
    __shared__ int rmin[4], rmax[4];
    const int wave = threadIdx.x >> 6;
    if ((threadIdx.x & 63) == 0) { rmin[wave] = vmin; rmax[wave] = vmax; }
    __syncthreads();
    if (threadIdx.x == 0) {
      pmin[blockIdx.x] = min(min(rmin[0], rmin[1]), min(rmin[2], rmin[3]));
      pmax[blockIdx.x] = max(max(rmax[0], rmax[1]), max(rmax[2], rmax[3]));
    }
  } else {
    const int wave = threadIdx.x >> 6;
    const int lane = threadIdx.x & 63;
    const int row = (blockIdx.x - NPART) * 4 + wave;
    const float4* xr = (const float4*)(x + (size_t)row * IN_F);
    ushort4* xbr = (ushort4*)(xb + (size_t)row * IN_F);
    float s = 0.f;
#pragma unroll
    for (int it = 0; it < IN_F / 4 / 64; ++it) {
      const int i = it * 64 + lane;
      float4 v = xr[i];
      s += (v.x + v.y) + (v.z + v.w);
      ushort4 h;
      h.x = f2bf_rne(v.x); h.y = f2bf_rne(v.y);
      h.z = f2bf_rne(v.z); h.w = f2bf_rne(v.w);
      xbr[i] = h;
    }
    for (int off = 32; off > 0; off >>= 1) s += __shfl_down(s, off);
    if (lane == 0) rowsum[row] = s;
  }
}

// ---------------- weight min/max only (fallback path, partials) ----------------
__global__ __launch_bounds__(256) void k_wmm(const int* __restrict__ q,
                                             int* __restrict__ pmin,
                                             int* __restrict__ pmax) {
  const int n4 = (OUT_F * IN_F) / 4;
  const int stride = gridDim.x * blockDim.x;
  int vmin = INT_MAX, vmax = INT_MIN;
  const int4* q4 = (const int4*)q;
  for (int i = blockIdx.x * blockDim.x + threadIdx.x; i < n4; i += stride) {
    int4 v = q4[i];
    vmin = min(vmin, min(min(v.x, v.y), min(v.z, v.w)));
    vmax = max(vmax, max(max(v.x, v.y), max(v.z, v.w)));
  }
  for (int off = 32; off > 0; off >>= 1) {
    vmin = min(vmin, __shfl_down(vmin, off));
    vmax = max(vmax, __shfl_down(vmax, off));
  }
  __shared__ int rmin[4], rmax[4];
  const int wave = threadIdx.x >> 6;
  if ((threadIdx.x & 63) == 0) { rmin[wave] = vmin; rmax[wave] = vmax; }
  __syncthreads();
  if (threadIdx.x == 0) {
    pmin[blockIdx.x] = min(min(rmin[0], rmin[1]), min(rmin[2], rmin[3]));
    pmax[blockIdx.x] = max(max(rmax[0], rmax[1]), max(rmax[2], rmax[3]));
  }
}

// ---------------- reduce partials + bias min/max, compute affine scalars ----------------
__global__ __launch_bounds__(256) void k_scal(const int* __restrict__ pmin,
                                              const int* __restrict__ pmax, int npart,
                                              const int* __restrict__ bq,
                                              const float* __restrict__ wmn,
                                              const float* __restrict__ wmx,
                                              const float* __restrict__ bmn,
                                              const float* __restrict__ bmx,
                                              float* __restrict__ scal) {
  int vmin = INT_MAX, vmax = INT_MIN;
  for (int i = threadIdx.x; i < npart; i += 256) {
    vmin = min(vmin, pmin[i]);
    vmax = max(vmax, pmax[i]);
  }
  int bmin = INT_MAX, bmaxv = INT_MIN;
  for (int i = threadIdx.x; i < OUT_F; i += 256) {
    int v = bq[i];
    bmin = min(bmin, v);
    bmaxv = max(bmaxv, v);
  }
  for (int off = 32; off > 0; off >>= 1) {
    vmin = min(vmin, __shfl_down(vmin, off));
    vmax = max(vmax, __shfl_down(vmax, off));
    bmin = min(bmin, __shfl_down(bmin, off));
    bmaxv = max(bmaxv, __shfl_down(bmaxv, off));
  }
  __shared__ int r[4][4];
  const int wave = threadIdx.x >> 6;
  if ((threadIdx.x & 63) == 0) {
    r[wave][0] = vmin; r[wave][1] = vmax; r[wave][2] = bmin; r[wave][3] = bmaxv;
  }
  __syncthreads();
  if (threadIdx.x == 0) {
    int qmin = min(min(r[0][0], r[1][0]), min(r[2][0], r[3][0]));
    int qmax = max(max(r[0][1], r[1][1]), max(r[2][1], r[3][1]));
    int qbmin = min(min(r[0][2], r[1][2]), min(r[2][2], r[3][2]));
    int qbmax = max(max(r[0][3], r[1][3]), max(r[2][3], r[3][3]));
    float ws = (*wmx - *wmn) / (float)(qmax - qmin);
    scal[0] = ws;
    scal[1] = *wmn - ws * (float)qmin;
    float bs = (*bmx - *bmn) / (float)(qbmax - qbmin);
    scal[2] = bs;
    scal[3] = *bmn - bs * (float)qbmin;
  }
}

// ---------------- async global->LDS, 16B per lane, wave-uniform LDS base ----------------
__device__ __forceinline__ void load_lds16(const unsigned short* g, unsigned short* l) {
  __builtin_amdgcn_global_load_lds(
      (const __attribute__((address_space(1))) unsigned int*)g,
      (__attribute__((address_space(3))) unsigned int*)l, 16, 0, 0);
}

// ---------------- 256x256-tile deep-pipelined bf16 MFMA GEMM: C = A @ B^T ----------------
// R6: add register-level fragment read-ahead (counted lgkmcnt via program order) so the
// LDS pipe (~1152 cyc/iter/CU) overlaps the matrix pipe (~1241 cyc/iter/CU). R5 measured
// 2794 cyc/iter = the fully-SERIALIZED sum (MfmaUtil 40%); reads-before-barrier +
// lgkm-drain-after-barrier was the structural stall. Now:
//   a2 reads + A-gloads -> C0 MFMA (lgkmcnt(4), a2 in flight)
//   next-iter frag reads + B-gloads -> C1 MFMA (lgkmcnt(8), next frags in flight)
//   vmcnt(4) -> barrier -> compiler fence.   One barrier per K-iteration.
// Safety (re-derived): end-of-t vmcnt(4) retires tiles <= t+2 BEFORE the barrier, so
// mid-iter-(t+1) reads of tile t+2 are block-wide safe; checkpoint must stay pre-barrier.
// Slot staged in iter t ((t-1)&3) was last read at top of iter t-1 and drained by that
// iter's C1 lgkm wait, pre-barrier. asm("":::"memory") after each raw s_barrier keeps
// gload issues from hoisting above the barrier (s_barrier is not an IR memory fence).
// Fragment double-buffers fa0/fb0 vs fa1/fb1 are statically indexed via 4x-unrolled
// bodies (rule 20). Tail: vmcnt(4)...vmcnt(0)@t=125, no stage/readahead past the end.
#define VMW(n) asm volatile("s_waitcnt vmcnt(" #n ")" ::: "memory")
#define CFENCE asm volatile("" ::: "memory")

#define GITER(C, CA, CB, NA, NB, PF, LDN, CHK)                                      \
  {                                                                                 \
    bf16x8 a2_[4];                                                                  \
    _Pragma("unroll") for (int i = 0; i < 4; ++i)                                   \
        a2_[i] = *(const bf16x8*)&As[(C)][(wm + 64 + i * 16 + r16) * 32 + pc];      \
    if (PF) {                                                                       \
      load_lds16(srcA0 + kb + ((C) + 3) * 32, &As[((C) + 3) & 3][dst0]);            \
      load_lds16(srcA1 + kb + ((C) + 3) * 32, &As[((C) + 3) & 3][dst1]);            \
    }                                                                               \
    __builtin_amdgcn_s_setprio(1);                                                  \
    _Pragma("unroll") for (int mi = 0; mi < 4; ++mi)                                \
        _Pragma("unroll") for (int ni = 0; ni < 4; ++ni)                            \
            acc[mi][ni] = __builtin_amdgcn_mfma_f32_16x16x32_bf16(                  \
                CA[mi], CB[ni], acc[mi][ni], 0, 0, 0);                              \
    __builtin_amdgcn_s_setprio(0);                                                  \
    if (LDN) {                                                                      \
      _Pragma("unroll") for (int i = 0; i < 4; ++i) {                               \
        NA[i] = *(const bf16x8*)&As[((C) + 1) & 3][(wm + i * 16 + r16) * 32 + pc];  \
        NB[i] = *(const bf16x8*)&Bs[((C) + 1) & 3][(wn + i * 16 + r16) * 32 + pc];  \
      }                                                                             \
    }                                                                               \
    if (PF) {                                                                       \
      load_lds16(srcB0 + kb + ((C) + 3) * 32, &Bs[((C) + 3) & 3][dst0]);            \
      load_lds16(srcB1 + kb + ((C) + 3) * 32, &Bs[((C) + 3) & 3][dst1]);            \
    }                                                                               \
    __builtin_amdgcn_s_setprio(1);                                                  \
    _Pragma("unroll") for (int mi = 0; mi < 4; ++mi)                                \
        _Pragma("unroll") for (int ni = 0; ni < 4; ++ni)                            \
            acc[4 + mi][ni] = __builtin_amdgcn_mfma_f32_16x16x32_bf16(              \
                a2_[mi], CB[ni], acc[4 + mi][ni], 0, 0, 0);                         \
    __builtin_amdgcn_s_setprio(0);                                                  \
    CHK;                                                                            \
    __builtin_amdgcn_s_barrier();                                                   \
    CFENCE;                                                                         \
  }

__global__ __launch_bounds__(512, 2) void k_gemm(
    const unsigned short* __restrict__ A,   // x   bf16 [BATCH][IN_F]
    const unsigned short* __restrict__ B,   // Q   bf16 [OUT_F][IN_F]
    const int* __restrict__ bq,
    const float* __restrict__ rowsum,
    const float* __restrict__ scal,
    float* __restrict__ C) {
  __shared__ __align__(16) unsigned short As[4][8192];   // 4 slots x 256 rows x 32 cols
  __shared__ __align__(16) unsigned short Bs[4][8192];

  const int tid = threadIdx.x;
  const int w = tid >> 6;
  const int lane = tid & 63;
  const int bm = blockIdx.x * 256;
  const int bn = blockIdx.y * 256;

  const int wm = (w & 1) * 128;    // wave's 128x64 output subtile
  const int wn = (w >> 1) * 64;
  const int r16 = lane & 15;
  const int q = lane >> 4;
  // fragment-read swizzled chunk (element offset): chunk q XOR row-bits
  const int pc = (q ^ ((r16 >> 1) & 3)) * 8;

  // staging assignment: wave w covers chunks [w*128, w*128+128) of each 1024-chunk slot
  const int cA0 = w * 128 + lane;
  const int rowS0 = cA0 >> 2;
  const int colS0 = ((cA0 & 3) ^ ((rowS0 >> 1) & 3)) * 8;   // pre-swizzled global source
  const int cA1 = cA0 + 64;
  const int rowS1 = cA1 >> 2;
  const int colS1 = ((cA1 & 3) ^ ((rowS1 >> 1) & 3)) * 8;
  const unsigned short* srcA0 = A + (size_t)(bm + rowS0) * IN_F + colS0;
  const unsigned short* srcA1 = A + (size_t)(bm + rowS1) * IN_F + colS1;
  const unsigned short* srcB0 = B + (size_t)(bn + rowS0) * IN_F + colS0;
  const unsigned short* srcB1 = B + (size_t)(bn + rowS1) * IN_F + colS1;
  const int dst0 = w * 1024;        // ushort offset of wave's chunk block, load 0
  const int dst1 = w * 1024 + 512;  // load 1

  f32x4 acc[8][4] = {};
  bf16x8 fa0[4], fb0[4], fa1[4], fb1[4];

  // prologue: stage tiles 0,1,2 into slots 0,1,2 (12 loads/thread)
#pragma unroll
  for (int t = 0; t < 3; ++t) {
    load_lds16(srcA0 + t * 32, &As[t][dst0]);
    load_lds16(srcA1 + t * 32, &As[t][dst1]);
    load_lds16(srcB0 + t * 32, &Bs[t][dst0]);
    load_lds16(srcB1 + t * 32, &Bs[t][dst1]);
  }
  VMW(4);   // tiles 0,1 retired (tile 2 in flight) — read-ahead consumes tile 1 mid-iter-0
  __builtin_amdgcn_s_barrier();
  CFENCE;
#pragma unroll
  for (int i = 0; i < 4; ++i) {
    fa0[i] = *(const bf16x8*)&As[0][(wm + i * 16 + r16) * 32 + pc];
    fb0[i] = *(const bf16x8*)&Bs[0][(wn + i * 16 + r16) * 32 + pc];
  }

  // steady state: iterations T = 4u + C, C compile-time -> static slots & reg buffers
  for (int u = 0; u < 31; ++u) {
    const int kb = u * 128;
    GITER(0, fa0, fb0, fa1, fb1, 1, 1, VMW(4));
    GITER(1, fa1, fb1, fa0, fb0, 1, 1, VMW(4));
    GITER(2, fa0, fb0, fa1, fb1, 1, 1, VMW(4));
    GITER(3, fa1, fb1, fa0, fb0, 1, 1, VMW(4));
  }
  // tail u = 31: T = 124..127
  {
    const int kb = 31 * 128;
    GITER(0, fa0, fb0, fa1, fb1, 1, 1, VMW(4));   // stages tile 127 (last)
    GITER(1, fa1, fb1, fa0, fb0, 0, 1, VMW(0));   // drain: tile 127 resident
    GITER(2, fa0, fb0, fa1, fb1, 0, 1, ((void)0));
    GITER(3, fa1, fb1, fa0, fb0, 0, 0, ((void)0));
  }

  const float wsc = scal[0], wbe = scal[1], bsc = scal[2], bbe = scal[3];
#pragma unroll
  for (int ni = 0; ni < 4; ++ni) {
    const int gn = bn + wn + ni * 16 + r16;            // C/D: col = lane&15
    const float bdq = bsc * (float)bq[gn] + bbe;
#pragma unroll
    for (int mi = 0; mi < 8; ++mi) {
      const int gm0 = bm + wm + mi * 16 + q * 4;       // C/D: row = quad*4 + reg
#pragma unroll
      for (int r = 0; r < 4; ++r) {
        const int gm = gm0 + r;
        C[(size_t)gm * OUT_F + gn] = wsc * acc[mi][ni][r] + wbe * rowsum[gm] + bdq;
      }
    }
  }
}

// ---------------- fallback (workspace too small): dequant-on-the-fly naive GEMM ----------------
__global__ void k_naive(const float* __restrict__ x, const int* __restrict__ wq,
                        const int* __restrict__ bq, const float* __restrict__ scal,
                        float* __restrict__ out) {
  const int o = blockIdx.x * blockDim.x + threadIdx.x;
  const int b = blockIdx.y;
  const float* xr = x + (size_t)b * IN_F;
  const int* wr = wq + (size_t)o * IN_F;
  float s = 0.f, sx = 0.f;
  for (int k = 0; k < IN_F; ++k) {
    float xv = xr[k];
    s += xv * (float)wr[k];
    sx += xv;
  }
  out[(size_t)b * OUT_F + o] =
      scal[0] * s + scal[1] * sx + scal[2] * (float)bq[o] + scal[3];
}

extern "C" void kernel_launch(void* const* d_in, const int* in_sizes, int n_in,
                              void* d_out, int out_size, void* d_ws, size_t ws_size,
                              hipStream_t stream) {
  const float* x = (const float*)d_in[0];
  const int* wq = (const int*)d_in[1];
  const int* bq = (const int*)d_in[2];
  const float* wmn = (const float*)d_in[3];
  const float* wmx = (const float*)d_in[4];
  const float* bmn = (const float*)d_in[5];
  const float* bmx = (const float*)d_in[6];
  float* out = (float*)d_out;

  char* ws = (char*)d_ws;
  float* scal = (float*)ws;                                  // 16 B
  int* pmin = (int*)(ws + 64);                               // 4 KB
  int* pmax = (int*)(ws + 64 + NPART * 4);                   // 4 KB
  float* rowsum = (float*)(ws + 64 + 2 * NPART * 4);         // 16 KB
  unsigned short* xb = (unsigned short*)(ws + 32768);
  unsigned short* qb = xb + (size_t)BATCH * IN_F;
  const size_t needed = 32768 + (size_t)BATCH * IN_F * 2 + (size_t)OUT_F * IN_F * 2;

  if (ws_size >= needed) {
    k_conv<<<2 * NPART, 256, 0, stream>>>(x, wq, xb, qb, rowsum, pmin, pmax);
    k_scal<<<1, 256, 0, stream>>>(pmin, pmax, NPART, bq, wmn, wmx, bmn, bmx, scal);
    dim3 grid(BATCH / 256, OUT_F / 256);
    k_gemm<<<grid, 512, 0, stream>>>(xb, qb, bq, rowsum, scal, out);
  } else {
    k_wmm<<<NPART, 256, 0, stream>>>(wq, pmin, pmax);
    k_scal<<<1, 256, 0, stream>>>(pmin, pmax, NPART, bq, wmn, wmx, bmn, bmx, scal);
    k_naive<<<dim3(OUT_F / 256, BATCH), 256, 0, stream>>>(x, wq, bq, scal, out);
  }
}

// Round 4
// 313.429 us; speedup vs baseline: 1.1291x; 1.0032x over previous
//
#include <hip/hip_runtime.h>
#include <climits>

#define IN_F 4096
#define OUT_F 4096
#define BATCH 4096
#define NPART 1024   // partial-reduction slots for weight min/max

typedef __bf16 bf16x8 __attribute__((ext_vector_type(8)));
typedef float f32x4 __attribute__((ext_vector_type(4)));

__device__ __forceinline__ unsigned short f2bf_rne(float f) {
  unsigned int u = __float_as_uint(f);
  u += 0x7fffu + ((u >> 16) & 1u);
  return (unsigned short)(u >> 16);
}

// ---------------- fused conversion kernel ----------------
// blocks [0, NPART):        weights int32 -> bf16 (exact), per-block partial min/max
// blocks [NPART, 2*NPART):  x fp32 -> bf16 + per-row sums (1 wave per row, 4 rows/block)
__global__ __launch_bounds__(256) void k_conv(const float* __restrict__ x,
                                              const int* __restrict__ q,
                                              unsigned short* __restrict__ xb,
                                              unsigned short* __restrict__ qb,
                                              float* __restrict__ rowsum,
                                              int* __restrict__ pmin,
                                              int* __restrict__ pmax) {
  if (blockIdx.x < NPART) {
    const int n4 = (OUT_F * IN_F) / 4;
    const int stride = NPART * 256;
    int vmin = INT_MAX, vmax = INT_MIN;
    const int4* q4 = (const int4*)q;
    ushort4* qb4 = (ushort4*)qb;
    for (int i = blockIdx.x * 256 + threadIdx.x; i < n4; i += stride) {
      int4 v = q4[i];
      vmin = min(vmin, min(min(v.x, v.y), min(v.z, v.w)));
      vmax = max(vmax, max(max(v.x, v.y), max(v.z, v.w)));
      ushort4 h;
      h.x = f2bf_rne((float)v.x);  // |q| <= 255 -> exact in bf16
      h.y = f2bf_rne((float)v.y);
      h.z = f2bf_rne((float)v.z);
      h.w = f2bf_rne((float)v.w);
      qb4[i] = h;
    }
    for (int off = 32; off > 0; off >>= 1) {
      vmin = min(vmin, __shfl_down(vmin, off));
      vmax = max(vmax, __shfl_down(vmax, off));
    }
    __shared__ int rmin[4], rmax[4];
    const int wave = threadIdx.x >> 6;
    if ((threadIdx.x & 63) == 0) { rmin[wave] = vmin; rmax[wave] = vmax; }
    __syncthreads();
    if (threadIdx.x == 0) {
      pmin[blockIdx.x] = min(min(rmin[0], rmin[1]), min(rmin[2], rmin[3]));
      pmax[blockIdx.x] = max(max(rmax[0], rmax[1]), max(rmax[2], rmax[3]));
    }
  } else {
    const int wave = threadIdx.x >> 6;
    const int lane = threadIdx.x & 63;
    const int row = (blockIdx.x - NPART) * 4 + wave;
    const float4* xr = (const float4*)(x + (size_t)row * IN_F);
    ushort4* xbr = (ushort4*)(xb + (size_t)row * IN_F);
    float s = 0.f;
#pragma unroll
    for (int it = 0; it < IN_F / 4 / 64; ++it) {
      const int i = it * 64 + lane;
      float4 v = xr[i];
      s += (v.x + v.y) + (v.z + v.w);
      ushort4 h;
      h.x = f2bf_rne(v.x); h.y = f2bf_rne(v.y);
      h.z = f2bf_rne(v.z); h.w = f2bf_rne(v.w);
      xbr[i] = h;
    }
    for (int off = 32; off > 0; off >>= 1) s += __shfl_down(s, off);
    if (lane == 0) rowsum[row] = s;
  }
}

// ---------------- weight min/max only (fallback path, partials) ----------------
__global__ __launch_bounds__(256) void k_wmm(const int* __restrict__ q,
                                             int* __restrict__ pmin,
                                             int* __restrict__ pmax) {
  const int n4 = (OUT_F * IN_F) / 4;
  const int stride = gridDim.x * blockDim.x;
  int vmin = INT_MAX, vmax = INT_MIN;
  const int4* q4 = (const int4*)q;
  for (int i = blockIdx.x * blockDim.x + threadIdx.x; i < n4; i += stride) {
    int4 v = q4[i];
    vmin = min(vmin, min(min(v.x, v.y), min(v.z, v.w)));
    vmax = max(vmax, max(max(v.x, v.y), max(v.z, v.w)));
  }
  for (int off = 32; off > 0; off >>= 1) {
    vmin = min(vmin, __shfl_down(vmin, off));
    vmax = max(vmax, __shfl_down(vmax, off));
  }
  __shared__ int rmin[4], rmax[4];
  const int wave = threadIdx.x >> 6;
  if ((threadIdx.x & 63) == 0) { rmin[wave] = vmin; rmax[wave] = vmax; }
  __syncthreads();
  if (threadIdx.x == 0) {
    pmin[blockIdx.x] = min(min(rmin[0], rmin[1]), min(rmin[2], rmin[3]));
    pmax[blockIdx.x] = max(max(rmax[0], rmax[1]), max(rmax[2], rmax[3]));
  }
}

// ---------------- reduce partials + bias min/max, compute affine scalars ----------------
__global__ __launch_bounds__(256) void k_scal(const int* __restrict__ pmin,
                                              const int* __restrict__ pmax, int npart,
                                              const int* __restrict__ bq,
                                              const float* __restrict__ wmn,
                                              const float* __restrict__ wmx,
                                              const float* __restrict__ bmn,
                                              const float* __restrict__ bmx,
                                              float* __restrict__ scal) {
  int vmin = INT_MAX, vmax = INT_MIN;
  for (int i = threadIdx.x; i < npart; i += 256) {
    vmin = min(vmin, pmin[i]);
    vmax = max(vmax, pmax[i]);
  }
  int bmin = INT_MAX, bmaxv = INT_MIN;
  for (int i = threadIdx.x; i < OUT_F; i += 256) {
    int v = bq[i];
    bmin = min(bmin, v);
    bmaxv = max(bmaxv, v);
  }
  for (int off = 32; off > 0; off >>= 1) {
    vmin = min(vmin, __shfl_down(vmin, off));
    vmax = max(vmax, __shfl_down(vmax, off));
    bmin = min(bmin, __shfl_down(bmin, off));
    bmaxv = max(bmaxv, __shfl_down(bmaxv, off));
  }
  __shared__ int r[4][4];
  const int wave = threadIdx.x >> 6;
  if ((threadIdx.x & 63) == 0) {
    r[wave][0] = vmin; r[wave][1] = vmax; r[wave][2] = bmin; r[wave][3] = bmaxv;
  }
  __syncthreads();
  if (threadIdx.x == 0) {
    int qmin = min(min(r[0][0], r[1][0]), min(r[2][0], r[3][0]));
    int qmax = max(max(r[0][1], r[1][1]), max(r[2][1], r[3][1]));
    int qbmin = min(min(r[0][2], r[1][2]), min(r[2][2], r[3][2]));
    int qbmax = max(max(r[0][3], r[1][3]), max(r[2][3], r[3][3]));
    float ws = (*wmx - *wmn) / (float)(qmax - qmin);
    scal[0] = ws;
    scal[1] = *wmn - ws * (float)qmin;
    float bs = (*bmx - *bmn) / (float)(qbmax - qbmin);
    scal[2] = bs;
    scal[3] = *bmn - bs * (float)qbmin;
  }
}

// ---------------- async global->LDS, 16B per lane, wave-uniform LDS base ----------------
__device__ __forceinline__ void load_lds16(const unsigned short* g, unsigned short* l) {
  __builtin_amdgcn_global_load_lds(
      (const __attribute__((address_space(1))) unsigned int*)g,
      (__attribute__((address_space(3))) unsigned int*)l, 16, 0, 0);
}

// ---------------- 256x256-tile deep-pipelined bf16 MFMA GEMM: C = A @ B^T ----------------
// R7: exact m201 phase rhythm. R5/R6 measured the SERIAL sum of LDS+MFMA pipes
// (2794/2580 cyc/iter vs ~1250 overlapped): raw s_barrier is NOT an IR memory fence,
// so the scheduler could sink the pre-barrier ds_reads below the barrier, defeating
// the barrier-wait-hides-LDS-latency mechanism. Fix = m201's missing ingredient:
//   reads; gload issues; CFENCE(pins reads above);  s_barrier;
//   asm lgkmcnt(0) ["memory"]  <- full fence, reads stay pre-barrier, wait is ~free;
//   setprio(1); 16 MFMA; setprio(0); s_barrier.
// Two such phases per K32-iter; counted vmcnt once per iter (never 0 in steady state).
// 4-slot LDS ring (A+B 32 KB/slot, 128 KB, 1 blk/CU), stage tile t+3 during iter t.
// Register read-ahead from R6 dropped (-32 VGPR, no 620-cyc read-to-consume chain).
//
// Invariants: slot being staged ((t-1)&3) was last ds_read in iter t-1, lgkm-drained
// before that phase's MFMA, >=1 barrier before the new DMA issues. End-of-iter
// vmcnt(8) retires tile t+1 (2-iter flight time) pre-barrier -> block-wide resident
// for iter t+1's reads. Tail: vmcnt(4) @ t=NT-3, vmcnt(0) @ t=NT-2.
// LDS swizzle (both-sides involution): 16B chunk p of row r holds k-chunk p^((r>>1)&3).
#define VMW(n) asm volatile("s_waitcnt vmcnt(" #n ")" ::: "memory")
#define LGKM0  asm volatile("s_waitcnt lgkmcnt(0)" ::: "memory")
#define CFENCE asm volatile("" ::: "memory")

__global__ __launch_bounds__(512, 2) void k_gemm(
    const unsigned short* __restrict__ A,   // x   bf16 [BATCH][IN_F]
    const unsigned short* __restrict__ B,   // Q   bf16 [OUT_F][IN_F]
    const int* __restrict__ bq,
    const float* __restrict__ rowsum,
    const float* __restrict__ scal,
    float* __restrict__ C) {
  __shared__ __align__(16) unsigned short As[4][8192];   // 4 slots x 256 rows x 32 cols
  __shared__ __align__(16) unsigned short Bs[4][8192];

  const int tid = threadIdx.x;
  const int w = tid >> 6;
  const int lane = tid & 63;
  const int bm = blockIdx.x * 256;
  const int bn = blockIdx.y * 256;

  const int wm = (w & 1) * 128;    // wave's 128x64 output subtile
  const int wn = (w >> 1) * 64;
  const int r16 = lane & 15;
  const int q = lane >> 4;
  // fragment-read swizzled chunk (element offset): chunk q XOR row-bits
  const int pc = (q ^ ((r16 >> 1) & 3)) * 8;

  // staging assignment: wave w covers chunks [w*128, w*128+128) of each 1024-chunk slot
  const int cA0 = w * 128 + lane;
  const int rowS0 = cA0 >> 2;
  const int colS0 = ((cA0 & 3) ^ ((rowS0 >> 1) & 3)) * 8;   // pre-swizzled global source
  const int cA1 = cA0 + 64;
  const int rowS1 = cA1 >> 2;
  const int colS1 = ((cA1 & 3) ^ ((rowS1 >> 1) & 3)) * 8;
  const unsigned short* srcA0 = A + (size_t)(bm + rowS0) * IN_F + colS0;
  const unsigned short* srcA1 = A + (size_t)(bm + rowS1) * IN_F + colS1;
  const unsigned short* srcB0 = B + (size_t)(bn + rowS0) * IN_F + colS0;
  const unsigned short* srcB1 = B + (size_t)(bn + rowS1) * IN_F + colS1;
  const int dst0 = w * 1024;        // ushort offset of wave's chunk block, load 0
  const int dst1 = w * 1024 + 512;  // load 1

  f32x4 acc[8][4] = {};

  const int NT = IN_F / 32;   // 128 K-subtiles

  // prologue: stage tiles 0,1,2 into slots 0,1,2 (12 loads/thread)
#pragma unroll
  for (int t = 0; t < 3; ++t) {
    load_lds16(srcA0 + t * 32, &As[t][dst0]);
    load_lds16(srcA1 + t * 32, &As[t][dst1]);
    load_lds16(srcB0 + t * 32, &Bs[t][dst0]);
    load_lds16(srcB1 + t * 32, &Bs[t][dst1]);
  }
  VMW(8);   // tile 0 resident (tiles 1,2 still in flight)
  __builtin_amdgcn_s_barrier();
  CFENCE;

  for (int t = 0; t < NT; ++t) {
    const int s = t & 3;
    const unsigned short* Asl = As[s];
    const unsigned short* Bsl = Bs[s];
    const int s3 = (t + 3) & 3;
    const int koff = (t + 3) * 32;
    const bool pf = (t + 3 < NT);

    // ---- phase 0: reads (A rows 0-63 of wave tile + all B) fly pre-barrier;
    //      A-halves of tile t+3 issued; MFMA after pinned lgkm drain ----
    bf16x8 afr[4], bfr[4];
#pragma unroll
    for (int i = 0; i < 4; ++i)
      afr[i] = *(const bf16x8*)&Asl[(wm + i * 16 + r16) * 32 + pc];
#pragma unroll
    for (int i = 0; i < 4; ++i)
      bfr[i] = *(const bf16x8*)&Bsl[(wn + i * 16 + r16) * 32 + pc];
    if (pf) {
      load_lds16(srcA0 + koff, &As[s3][dst0]);
      load_lds16(srcA1 + koff, &As[s3][dst1]);
    }
    CFENCE;                           // pin reads + load issues above the barrier
    __builtin_amdgcn_s_barrier();
    LGKM0;                            // reads completed during barrier wait; full fence
    __builtin_amdgcn_s_setprio(1);
#pragma unroll
    for (int mi = 0; mi < 4; ++mi)
#pragma unroll
      for (int ni = 0; ni < 4; ++ni)
        acc[mi][ni] = __builtin_amdgcn_mfma_f32_16x16x32_bf16(afr[mi], bfr[ni], acc[mi][ni], 0, 0, 0);
    __builtin_amdgcn_s_setprio(0);
    __builtin_amdgcn_s_barrier();

    // ---- phase 1: reads (A rows 64-127, B reused); B-halves of tile t+3 ----
    bf16x8 af2[4];
#pragma unroll
    for (int i = 0; i < 4; ++i)
      af2[i] = *(const bf16x8*)&Asl[(wm + 64 + i * 16 + r16) * 32 + pc];
    if (pf) {
      load_lds16(srcB0 + koff, &Bs[s3][dst0]);
      load_lds16(srcB1 + koff, &Bs[s3][dst1]);
    }
    CFENCE;
    __builtin_amdgcn_s_barrier();
    LGKM0;
    __builtin_amdgcn_s_setprio(1);
#pragma unroll
    for (int mi = 0; mi < 4; ++mi)
#pragma unroll
      for (int ni = 0; ni < 4; ++ni)
        acc[4 + mi][ni] = __builtin_amdgcn_mfma_f32_16x16x32_bf16(af2[mi], bfr[ni], acc[4 + mi][ni], 0, 0, 0);
    __builtin_amdgcn_s_setprio(0);

    // ---- counted-vmcnt checkpoint: tile t+1 retired; t+2/t+3 stay in flight ----
    if (t < NT - 3)       VMW(8);
    else if (t == NT - 3) VMW(4);
    else if (t == NT - 2) VMW(0);
    __builtin_amdgcn_s_barrier();
    CFENCE;
  }

  const float wsc = scal[0], wbe = scal[1], bsc = scal[2], bbe = scal[3];
#pragma unroll
  for (int ni = 0; ni < 4; ++ni) {
    const int gn = bn + wn + ni * 16 + r16;            // C/D: col = lane&15
    const float bdq = bsc * (float)bq[gn] + bbe;
#pragma unroll
    for (int mi = 0; mi < 8; ++mi) {
      const int gm0 = bm + wm + mi * 16 + q * 4;       // C/D: row = quad*4 + reg
#pragma unroll
      for (int r = 0; r < 4; ++r) {
        const int gm = gm0 + r;
        C[(size_t)gm * OUT_F + gn] = wsc * acc[mi][ni][r] + wbe * rowsum[gm] + bdq;
      }
    }
  }
}

// ---------------- fallback (workspace too small): dequant-on-the-fly naive GEMM ----------------
__global__ void k_naive(const float* __restrict__ x, const int* __restrict__ wq,
                        const int* __restrict__ bq, const float* __restrict__ scal,
                        float* __restrict__ out) {
  const int o = blockIdx.x * blockDim.x + threadIdx.x;
  const int b = blockIdx.y;
  const float* xr = x + (size_t)b * IN_F;
  const int* wr = wq + (size_t)o * IN_F;
  float s = 0.f, sx = 0.f;
  for (int k = 0; k < IN_F; ++k) {
    float xv = xr[k];
    s += xv * (float)wr[k];
    sx += xv;
  }
  out[(size_t)b * OUT_F + o] =
      scal[0] * s + scal[1] * sx + scal[2] * (float)bq[o] + scal[3];
}

extern "C" void kernel_launch(void* const* d_in, const int* in_sizes, int n_in,
                              void* d_out, int out_size, void* d_ws, size_t ws_size,
                              hipStream_t stream) {
  const float* x = (const float*)d_in[0];
  const int* wq = (const int*)d_in[1];
  const int* bq = (const int*)d_in[2];
  const float* wmn = (const float*)d_in[3];
  const float* wmx = (const float*)d_in[4];
  const float* bmn = (const float*)d_in[5];
  const float* bmx = (const float*)d_in[6];
  float* out = (float*)d_out;

  char* ws = (char*)d_ws;
  float* scal = (float*)ws;                                  // 16 B
  int* pmin = (int*)(ws + 64);                               // 4 KB
  int* pmax = (int*)(ws + 64 + NPART * 4);                   // 4 KB
  float* rowsum = (float*)(ws + 64 + 2 * NPART * 4);         // 16 KB
  unsigned short* xb = (unsigned short*)(ws + 32768);
  unsigned short* qb = xb + (size_t)BATCH * IN_F;
  const size_t needed = 32768 + (size_t)BATCH * IN_F * 2 + (size_t)OUT_F * IN_F * 2;

  if (ws_size >= needed) {
    k_conv<<<2 * NPART, 256, 0, stream>>>(x, wq, xb, qb, rowsum, pmin, pmax);
    k_scal<<<1, 256, 0, stream>>>(pmin, pmax, NPART, bq, wmn, wmx, bmn, bmx, scal);
    dim3 grid(BATCH / 256, OUT_F / 256);
    k_gemm<<<grid, 512, 0, stream>>>(xb, qb, bq, rowsum, scal, out);
  } else {
    k_wmm<<<NPART, 256, 0, stream>>>(wq, pmin, pmax);
    k_scal<<<1, 256, 0, stream>>>(pmin, pmax, NPART, bq, wmn, wmx, bmn, bmx, scal);
    k_naive<<<dim3(OUT_F / 256, BATCH), 256, 0, stream>>>(x, wq, bq, scal, out);
  }
}